// Round 9
// baseline (222.058 us; speedup 1.0000x reference)
//
#include <hip/hip_runtime.h>
#include <math.h>

#define N_NODES 50000
#define N_EDGES 600000
#define NFEAT   256
#define NHID    128
#define NCLASS  40
#define NBUCK 196            // bucket = dst >> 8 (256-node windows)
#define EPB_A 2048           // edges per phase-A block
#define BUCK_CAP 4096        // staging capacity per bucket (mean ~3062)
#define BUCK_WIN 5888        // fixed CSR window per bucket >= BUCK_CAP + 7*256 (mult of 8)
#define BINA_BLOCKS ((N_EDGES + EPB_A - 1) / EPB_A)   // 293
#define CVTW_BLOCKS 224                               // 57344 weight elems / 256
#define GEMM_BLOCKS ((N_NODES + 63) / 64)             // 782   (GEMM1 64-row tiles)
#define TILE_BLOCKS ((N_NODES + 31) / 32)             // 1563  (fused 32-row tiles)

typedef __attribute__((ext_vector_type(8))) short bf16x8;
typedef __attribute__((ext_vector_type(4))) float f32x4;
typedef __attribute__((ext_vector_type(2))) float f32x2;

__device__ inline ushort f2bf(float f) {   // RNE, finite inputs
    uint u = __float_as_uint(f);
    uint r = (u + 0x7fffu + ((u >> 16) & 1u)) >> 16;
    return (ushort)r;
}

// ---------------------------------------------------------------------------
// K1: blocks [0, BINA_BLOCKS) bin edges by 256-node bucket into fixed-capacity
// staging regions (record: uint = (bf16(w)<<16) | src; entry {rec, dst&255}).
// Blocks [BINA_BLOCKS, +CVTW_BLOCKS) convert the three weight matrices to
// transposed bf16.
__global__ __launch_bounds__(256) void binA_cvtw(const int* __restrict__ src,
                                                 const int* __restrict__ dst,
                                                 const float* __restrict__ w,
                                                 int* __restrict__ bucket_cnt,
                                                 int2* __restrict__ staging, int E,
                                                 const float* __restrict__ W1,
                                                 const float* __restrict__ W2,
                                                 const float* __restrict__ W3,
                                                 ushort* __restrict__ BT1,
                                                 ushort* __restrict__ BT2,
                                                 ushort* __restrict__ BT3) {
    int tid = threadIdx.x;
    if ((int)blockIdx.x >= BINA_BLOCKS) {
        int idx = ((int)blockIdx.x - BINA_BLOCKS) * 256 + tid;
        if (idx < 32768) {                       // BT1: 128x256 from W1[256x128]
            int nr = idx >> 8, k = idx & 255;
            BT1[idx] = f2bf(W1[(size_t)k * 128 + nr]);
        } else if (idx < 49152) {                // BT2: 128x128 from W2[128x128]
            int t = idx - 32768;
            int nr = t >> 7, k = t & 127;
            BT2[t] = f2bf(W2[(size_t)k * 128 + nr]);
        } else if (idx < 57344) {                // BT3: 64x128 from W3[128x40], zero-pad
            int t = idx - 49152;
            int nr = t >> 7, k = t & 127;
            BT3[t] = (nr < 40) ? f2bf(W3[(size_t)k * 40 + nr]) : (ushort)0;
        }
        return;
    }
    __shared__ int lh[NBUCK];
    for (int b = tid; b < NBUCK; b += 256) lh[b] = 0;
    __syncthreads();
    int base = blockIdx.x * EPB_A;
    int d[8];
    #pragma unroll
    for (int j = 0; j < 8; ++j) {
        int i = base + j * 256 + tid;
        d[j] = (i < E) ? dst[i] : -1;
        if (d[j] >= 0) atomicAdd(&lh[d[j] >> 8], 1);
    }
    __syncthreads();
    for (int b = tid; b < NBUCK; b += 256) {
        int c = lh[b];
        lh[b] = c ? (b * BUCK_CAP + atomicAdd(&bucket_cnt[b], c)) : 0;
    }
    __syncthreads();
    #pragma unroll
    for (int j = 0; j < 8; ++j) {
        int i = base + j * 256 + tid;
        if (d[j] >= 0) {
            int slot = atomicAdd(&lh[d[j] >> 8], 1);
            uint rec = ((uint)f2bf(w[i]) << 16) | (uint)src[i];
            staging[slot] = make_int2((int)rec, d[j] & 255);
        }
    }
}

// ---------------------------------------------------------------------------
// bf16 MFMA GEMM body (global-A variant, used for GEMM1 only; 64-row tiles).
template<int NT, bool AF32>
__device__ __forceinline__ void gemm_body(const void* __restrict__ Ain,
                                          const ushort* __restrict__ BT,
                                          int M, int K, int Nout,
                                          ushort* __restrict__ Cout, int row0) {
    __shared__ ushort a_s[64 * 40];
    __shared__ ushort b_s[64 * NT * 40];
    int tid = threadIdx.x;
    int wave = tid >> 6, lane = tid & 63;
    int lr = lane & 15, lk = (lane >> 4) * 8;
    f32x4 acc[4][NT];
    #pragma unroll
    for (int mt = 0; mt < 4; ++mt)
        #pragma unroll
        for (int nt = 0; nt < NT; ++nt) acc[mt][nt] = (f32x4){0.f, 0.f, 0.f, 0.f};

    for (int k0 = 0; k0 < K; k0 += 32) {
        {   // A tile: 64 rows x 32 k, 8 elems/thread
            int r = tid >> 2, c8 = (tid & 3) * 8;
            int gr = row0 + r; if (gr >= M) gr = M - 1;  // clamp, store-guarded
            if (AF32) {
                const float* Af = (const float*)Ain;
                float4 v0 = *(const float4*)(Af + (size_t)gr * K + k0 + c8);
                float4 v1 = *(const float4*)(Af + (size_t)gr * K + k0 + c8 + 4);
                ushort4 o0, o1;
                o0.x = f2bf(v0.x); o0.y = f2bf(v0.y); o0.z = f2bf(v0.z); o0.w = f2bf(v0.w);
                o1.x = f2bf(v1.x); o1.y = f2bf(v1.y); o1.z = f2bf(v1.z); o1.w = f2bf(v1.w);
                *(ushort4*)(a_s + r * 40 + c8) = o0;
                *(ushort4*)(a_s + r * 40 + c8 + 4) = o1;
            } else {
                const ushort* Ab = (const ushort*)Ain;
                float4 v = *(const float4*)(Ab + (size_t)gr * K + k0 + c8);
                *(float4*)(a_s + r * 40 + c8) = v;
            }
        }
        #pragma unroll
        for (int i = 0; i < NT; ++i) {  // BT tile: 64*NT rows x 32 k
            int idx = tid * NT + i;
            int r = idx >> 2, c8 = (idx & 3) * 8;
            float4 v = *(const float4*)(BT + (size_t)r * K + k0 + c8);
            *(float4*)(b_s + r * 40 + c8) = v;
        }
        __syncthreads();
        bf16x8 bfr[NT];
        #pragma unroll
        for (int nt = 0; nt < NT; ++nt)
            bfr[nt] = *(const bf16x8*)(b_s + ((wave * NT + nt) * 16 + lr) * 40 + lk);
        #pragma unroll
        for (int mt = 0; mt < 4; ++mt) {
            bf16x8 afr = *(const bf16x8*)(a_s + (mt * 16 + lr) * 40 + lk);
            #pragma unroll
            for (int nt = 0; nt < NT; ++nt)
                acc[mt][nt] = __builtin_amdgcn_mfma_f32_16x16x32_bf16(
                    afr, bfr[nt], acc[mt][nt], 0, 0, 0);
        }
        __syncthreads();
    }
    // C/D layout: col = lane&15, row = (lane>>4)*4 + i
    int col0 = wave * NT * 16;
    #pragma unroll
    for (int mt = 0; mt < 4; ++mt) {
        int gr0 = row0 + mt * 16 + (lane >> 4) * 4;
        #pragma unroll
        for (int nt = 0; nt < NT; ++nt) {
            int gc = col0 + nt * 16 + lr;
            #pragma unroll
            for (int i = 0; i < 4; ++i) {
                int gr = gr0 + i;
                if (gr < M && gc < Nout)
                    Cout[(size_t)gr * Nout + gc] = f2bf(acc[mt][nt][i]);
            }
        }
    }
}

// ---------------------------------------------------------------------------
// K2: blocks [0, NBUCK) do self-contained per-bucket scan+scatter into FIXED
// windows (gaps never read -> no global prefix). Blocks [NBUCK, +782) run
// GEMM1 (x fp32 -> supA bf16), overlapping the CSR tail.
// ROUND-9: the 256-step Hillis-Steele scan (512 barriers/block) is replaced
// by a shfl_up wave scan + 4-entry cross-wave combine (1 barrier).
__global__ __launch_bounds__(256) void scan_gemm1(const int* __restrict__ bucket_cnt,
                                                  const int2* __restrict__ staging,
                                                  int2* __restrict__ rsp2,
                                                  uint* __restrict__ edges,
                                                  const float* __restrict__ x,
                                                  const ushort* __restrict__ BT1,
                                                  ushort* __restrict__ supA) {
    if ((int)blockIdx.x >= NBUCK) {
        gemm_body<2, true>(x, BT1, N_NODES, 256, 128, supA,
                           ((int)blockIdx.x - NBUCK) * 64);
        return;
    }
    __shared__ int hist[256];
    __shared__ int lcur[256];
    __shared__ int wsum[4];
    int tid = threadIdx.x;
    hist[tid] = 0;
    __syncthreads();
    int b = blockIdx.x;
    int c = bucket_cnt[b];
    const int2* st = staging + (size_t)b * BUCK_CAP;
    for (int p = tid; p < c; p += 256) atomicAdd(&hist[st[p].y], 1);
    __syncthreads();
    int v = (hist[tid] + 7) & ~7;   // pad per-node count to multiple of 8
    int lane = tid & 63, wv = tid >> 6;
    int s = v;                      // wave-level inclusive scan (no barriers)
    #pragma unroll
    for (int off = 1; off < 64; off <<= 1) {
        int t = __shfl_up(s, off, 64);
        if (lane >= off) s += t;
    }
    if (lane == 63) wsum[wv] = s;
    __syncthreads();
    int woff = 0;
    #pragma unroll
    for (int j = 0; j < 4; ++j) woff += (j < wv) ? wsum[j] : 0;
    int tot = wsum[0] + wsum[1] + wsum[2] + wsum[3];
    int bb = b * BUCK_WIN;
    int ex = s - v + woff + bb;     // exclusive scan + bucket base
    int i = b * 256 + tid;
    if (i < N_NODES) rsp2[i] = make_int2(ex, ex + v);
    lcur[tid] = ex;
    __syncthreads();
    int e0 = bb + tot;
    for (int p = bb + tid; p < e0; p += 256) edges[p] = 0;   // covers padding
    __syncthreads();
    for (int p = tid; p < c; p += 256) {
        int2 r = st[p];
        int slot = atomicAdd(&lcur[r.y], 1);
        edges[slot] = (uint)r.x;
    }
}

// ---------------------------------------------------------------------------
// Flattened-stream engine, ROUND-9: depth-3 gather pipeline.
// Records wave-uniform -> SGPRs via readfirstlane'd base (4 rotating buffers,
// loaded 3 chunks ahead); gathers issued 2 chunk-steps before consumption
// (3 rotating value buffers) -> 2x in-flight gathers per wave vs round 8.
// 12-phase unrolled rotation (lcm of 3 and 4).

#define LDREC_S(R, POS) do { \
    int _ub = __builtin_amdgcn_readfirstlane(POS); \
    _Pragma("unroll") \
    for (int _i = 0; _i < 16; ++_i) R[_i] = edges[_ub + _i]; \
} while (0)

#define GATHER_S(P, R) do { \
    _Pragma("unroll") \
    for (int _j = 0; _j < 16; ++_j) { \
        uint _idx = R[_j] & 0xffffu; \
        _idx = (_idx < N_NODES) ? _idx : (N_NODES - 1);  /* SALU clamp */ \
        P[_j] = sup[(size_t)_idx * 64 + lane]; \
    } \
} while (0)

#define FLUSH_A() do { \
    uint _pk = ((uint)f2bf(fmaxf(acc2.y + by, 0.f)) << 16) \
             |  (uint)f2bf(fmaxf(acc2.x + bx, 0.f)); \
    *(uint*)(&a4_s[ks][(wave * 8 + cur) * 40 + kk]) = _pk; \
    acc2 = (f32x2){0.f, 0.f}; \
    ++cur; \
    e_cur = (cur < 8) ? e_s[wave][cur + 1] : 0x7fffffff; \
} while (0)

#define FMA_A(QB, P, R) do { \
    _Pragma("unroll") \
    for (int _g = 0; _g < 2; ++_g) { \
        int _qg = (QB) + _g * 8; \
        while (cur < 8 && _qg >= e_cur) FLUSH_A(); \
        if (_qg < QE) { \
            _Pragma("unroll") \
            for (int _j = 0; _j < 8; ++_j) { \
                uint _pv = P[_g * 8 + _j]; \
                float _w = __uint_as_float(R[_g * 8 + _j] & 0xffff0000u); \
                f32x2 _v; \
                _v.x = __uint_as_float(_pv << 16); \
                _v.y = __uint_as_float(_pv & 0xffff0000u); \
                acc2 += _v * (f32x2){_w, _w}; \
            } \
        } \
    } \
} while (0)

// phase i: LDREC(R[(i+3)%4], q+48); GATHER(P[(i+2)%3], R[(i+2)%4]);
//          FMA(q, P[i%3], R[i%4]); q += 16
#define PIPE12(GTH, FMA) \
    while (q < QE) { \
        LDREC_S(rd, q + 48); GTH(pc, rc); FMA(q, pa, ra); \
        q += 16; if (q >= QE) break; \
        LDREC_S(ra, q + 48); GTH(pa, rd); FMA(q, pb, rb); \
        q += 16; if (q >= QE) break; \
        LDREC_S(rb, q + 48); GTH(pb, ra); FMA(q, pc, rc); \
        q += 16; if (q >= QE) break; \
        LDREC_S(rc, q + 48); GTH(pc, rb); FMA(q, pa, rd); \
        q += 16; if (q >= QE) break; \
        LDREC_S(rd, q + 48); GTH(pa, rc); FMA(q, pb, ra); \
        q += 16; if (q >= QE) break; \
        LDREC_S(ra, q + 48); GTH(pb, rd); FMA(q, pc, rb); \
        q += 16; if (q >= QE) break; \
        LDREC_S(rb, q + 48); GTH(pc, ra); FMA(q, pa, rc); \
        q += 16; if (q >= QE) break; \
        LDREC_S(rc, q + 48); GTH(pa, rb); FMA(q, pb, rd); \
        q += 16; if (q >= QE) break; \
        LDREC_S(rd, q + 48); GTH(pb, rc); FMA(q, pc, ra); \
        q += 16; if (q >= QE) break; \
        LDREC_S(ra, q + 48); GTH(pc, rd); FMA(q, pa, rb); \
        q += 16; if (q >= QE) break; \
        LDREC_S(rb, q + 48); GTH(pa, ra); FMA(q, pb, rc); \
        q += 16; if (q >= QE) break; \
        LDREC_S(rc, q + 48); GTH(pb, rb); FMA(q, pc, rd); \
        q += 16; \
    }

template<int NT>
__device__ __forceinline__ void fused_body(const uint* __restrict__ sup,
                                           const int2* __restrict__ rsp2,
                                           const uint* __restrict__ edges,
                                           const float* __restrict__ bias,
                                           const ushort* __restrict__ BT,
                                           int Nout,
                                           ushort* __restrict__ Cout) {
    __shared__ ushort a4_s[4][32 * 40];
    __shared__ int e_s[4][9];      // [0]=stream start; [i+1]=end of node i
    int tid = threadIdx.x;
    int wave = tid >> 6, lane = tid & 63;
    int row0 = blockIdx.x * 32;
    int nfirst = row0 + wave * 8;
    float bx = bias[2 * lane], by = bias[2 * lane + 1];
    int ks = lane >> 4;            // k-subtile of this lane's feature pair
    int kk = 2 * (lane & 15);      // k offset within the subtile

    if (lane < 8) {
        int nd = nfirst + lane; if (nd >= N_NODES) nd = N_NODES - 1;
        int2 t = rsp2[nd];
        e_s[wave][lane + 1] = t.y;
        if (lane == 0) e_s[wave][0] = t.x;
    }
    __syncthreads();
    int Q = e_s[wave][0], QE = e_s[wave][8];
    int cur = 0, e_cur = e_s[wave][1];
    f32x2 acc2 = (f32x2){0.f, 0.f};

    uint ra[16], rb[16], rc[16], rd[16];   // uniform records -> SGPRs
    uint pa[16], pb[16], pc[16];
    int q = Q;
    // prologue (over-reads clamped/guarded; stay inside workspace)
    LDREC_S(ra, q);
    LDREC_S(rb, q + 16);
    LDREC_S(rc, q + 32);
    GATHER_S(pa, ra);
    GATHER_S(pb, rb);
    PIPE12(GATHER_S, FMA_A)
    while (cur < 8) FLUSH_A();                // finalize remaining nodes
    __syncthreads();

    // GEMM: C[32 x Nout] = A(LDS) @ BT^T, K = 128.
    int lr = lane & 15, lk = (lane >> 4) * 8;
    f32x4 acc[2][NT];
    #pragma unroll
    for (int mt = 0; mt < 2; ++mt)
        #pragma unroll
        for (int nt = 0; nt < NT; ++nt) acc[mt][nt] = (f32x4){0.f, 0.f, 0.f, 0.f};
    #pragma unroll
    for (int ksi = 0; ksi < 4; ++ksi) {
        int k0 = ksi * 32;
        bf16x8 bfr[NT];
        #pragma unroll
        for (int nt = 0; nt < NT; ++nt)
            bfr[nt] = *(const bf16x8*)(BT +
                (size_t)((wave * NT + nt) * 16 + lr) * 128 + k0 + lk);
        #pragma unroll
        for (int mt = 0; mt < 2; ++mt) {
            bf16x8 afr = *(const bf16x8*)(&a4_s[ksi][(mt * 16 + lr) * 40 + lk]);
            #pragma unroll
            for (int nt = 0; nt < NT; ++nt)
                acc[mt][nt] = __builtin_amdgcn_mfma_f32_16x16x32_bf16(
                    afr, bfr[nt], acc[mt][nt], 0, 0, 0);
        }
    }
    int col0 = wave * NT * 16;
    #pragma unroll
    for (int mt = 0; mt < 2; ++mt) {
        int gr0 = row0 + mt * 16 + (lane >> 4) * 4;
        #pragma unroll
        for (int nt = 0; nt < NT; ++nt) {
            int gc = col0 + nt * 16 + lr;
            #pragma unroll
            for (int i = 0; i < 4; ++i) {
                int gr = gr0 + i;
                if (gr < N_NODES && gc < Nout)
                    Cout[(size_t)gr * Nout + gc] = f2bf(acc[mt][nt][i]);
            }
        }
    }
}

__global__ __launch_bounds__(256) void fused_ag2(const uint* __restrict__ sup,
                                                 const int2* __restrict__ rsp2,
                                                 const uint* __restrict__ edges,
                                                 const float* __restrict__ bias,
                                                 const ushort* __restrict__ BT,
                                                 ushort* __restrict__ Cout) {
    fused_body<2>(sup, rsp2, edges, bias, BT, 128, Cout);
}

__global__ __launch_bounds__(256) void fused_ag3(const uint* __restrict__ sup,
                                                 const int2* __restrict__ rsp2,
                                                 const uint* __restrict__ edges,
                                                 const float* __restrict__ bias,
                                                 const ushort* __restrict__ BT,
                                                 ushort* __restrict__ Cout) {
    fused_body<1>(sup, rsp2, edges, bias, BT, 64, Cout);   // F=64, cols 40..63 zero
}

// ---------------------------------------------------------------------------
// Layer 3 aggregation + bias + log_softmax, flattened-stream, scalarized
// records, depth-3 pipeline. sup3 is F=64 natural layout (cols 40..63 zero).

#define GATHER_L(P, R) do { \
    _Pragma("unroll") \
    for (int _j = 0; _j < 16; ++_j) { \
        uint _idx = R[_j] & 0xffffu; \
        _idx = (_idx < N_NODES) ? _idx : (N_NODES - 1); \
        P[_j] = __uint_as_float((uint)sup[(size_t)_idx * 64 + lane] << 16); \
    } \
} while (0)

#define FLUSH_L() do { \
    int _node = nfirst + cur; \
    float _v = (lane < 40) ? acc1 + bl : -INFINITY; \
    float _m = _v; \
    _Pragma("unroll") \
    for (int _o = 32; _o; _o >>= 1) _m = fmaxf(_m, __shfl_xor(_m, _o, 64)); \
    float _ex = (lane < 40) ? expf(_v - _m) : 0.f; \
    float _s = _ex; \
    _Pragma("unroll") \
    for (int _o = 32; _o; _o >>= 1) _s += __shfl_xor(_s, _o, 64); \
    float _ls = logf(_s); \
    if (lane < 40 && _node < N_NODES) \
        out[(size_t)_node * 40 + lane] = _v - _m - _ls; \
    acc1 = 0.f; \
    ++cur; \
    e_cur = (cur < 8) ? e_s[wave][cur + 1] : 0x7fffffff; \
} while (0)

#define FMA_L(QB, P, R) do { \
    _Pragma("unroll") \
    for (int _g = 0; _g < 2; ++_g) { \
        int _qg = (QB) + _g * 8; \
        while (cur < 8 && _qg >= e_cur) FLUSH_L(); \
        if (_qg < QE) { \
            _Pragma("unroll") \
            for (int _j = 0; _j < 8; ++_j) \
                acc1 += P[_g * 8 + _j] * \
                        __uint_as_float(R[_g * 8 + _j] & 0xffff0000u); \
        } \
    } \
} while (0)

__global__ __launch_bounds__(256) void agg_lsm(const ushort* __restrict__ sup,
                                               const int2* __restrict__ rsp2,
                                               const uint* __restrict__ edges,
                                               const float* __restrict__ bias,
                                               float* __restrict__ out) {
    __shared__ int e_s[4][9];
    int tid = threadIdx.x;
    int wave = tid >> 6, lane = tid & 63;
    int nfirst = blockIdx.x * 32 + wave * 8;
    float bl = (lane < 40) ? bias[lane] : 0.f;
    if (lane < 8) {
        int nd = nfirst + lane; if (nd >= N_NODES) nd = N_NODES - 1;
        int2 t = rsp2[nd];
        e_s[wave][lane + 1] = t.y;
        if (lane == 0) e_s[wave][0] = t.x;
    }
    __syncthreads();
    int Q = e_s[wave][0], QE = e_s[wave][8];
    int cur = 0, e_cur = e_s[wave][1];
    float acc1 = 0.f;

    uint ra[16], rb[16], rc[16], rd[16];
    float pa[16], pb[16], pc[16];
    int q = Q;
    LDREC_S(ra, q);
    LDREC_S(rb, q + 16);
    LDREC_S(rc, q + 32);
    GATHER_L(pa, ra);
    GATHER_L(pb, rb);
    PIPE12(GATHER_L, FMA_L)
    while (cur < 8) FLUSH_L();
}

// ---------------------------------------------------------------------------
extern "C" void kernel_launch(void* const* d_in, const int* in_sizes, int n_in,
                              void* d_out, int out_size, void* d_ws, size_t ws_size,
                              hipStream_t stream) {
    const float* x   = (const float*)d_in[0];
    const float* ew  = (const float*)d_in[1];
    const float* W1  = (const float*)d_in[2];
    const float* b1  = (const float*)d_in[3];
    const float* W2  = (const float*)d_in[4];
    const float* b2  = (const float*)d_in[5];
    const float* W3  = (const float*)d_in[6];
    const float* b3  = (const float*)d_in[7];
    const int* esrc  = (const int*)d_in[8];
    const int* edst  = (const int*)d_in[9];
    float* out = (float*)d_out;

    char* ws = (char*)d_ws;
    size_t off = 0;
    auto alloc = [&](size_t bytes) {
        size_t cur = off;
        off += (bytes + 255) & ~(size_t)255;
        return cur;
    };
    int* bucket_cnt = (int*)(ws + alloc(256 * sizeof(int)));
    int2* rsp2   = (int2*)(ws + alloc((size_t)N_NODES * sizeof(int2)));          // 400 KB
    uint* edges  = (uint*)(ws + alloc((size_t)NBUCK * BUCK_WIN * sizeof(uint))); // 4.6 MB
    int2* staging = (int2*)(ws + alloc((size_t)NBUCK * BUCK_CAP * sizeof(int2))); // 6.4 MB
    ushort* BT1  = (ushort*)(ws + alloc(128 * 256 * 2));
    ushort* BT2  = (ushort*)(ws + alloc(128 * 128 * 2));
    ushort* BT3  = (ushort*)(ws + alloc(64 * 128 * 2));
    char* Sreg   = ws + alloc((size_t)N_NODES * 128 * 2);       // 12.8 MB
    char* Hreg   = ws + alloc((size_t)N_NODES * 128 * 2);       // 12.8 MB
    (void)alloc((size_t)66000 * 128 * 2);   // clamp-gather slack past Hreg

    ushort* supA = (ushort*)Sreg;                  // gemm1 out
    ushort* supB = (ushort*)Hreg;                  // fused ag2 out
    ushort* sup3 = (ushort*)Sreg;                  // fused ag3 out (supA dead), F=64

    hipMemsetAsync(bucket_cnt, 0, 256 * sizeof(int), stream);
    // K1: edge binning || weight conversion
    binA_cvtw<<<BINA_BLOCKS + CVTW_BLOCKS, 256, 0, stream>>>(
        esrc, edst, ew, bucket_cnt, staging, N_EDGES, W1, W2, W3, BT1, BT2, BT3);
    // K2: per-bucket scan+scatter (fixed windows) || GEMM1
    scan_gemm1<<<NBUCK + GEMM_BLOCKS, 256, 0, stream>>>(
        bucket_cnt, staging, rsp2, edges, x, BT1, supA);
    // K3: [agg1 + b1 + relu] -> GEMM x BT2 -> supB
    fused_ag2<<<TILE_BLOCKS, 256, 0, stream>>>(
        (const uint*)supA, rsp2, edges, b1, BT2, supB);
    // K4: [agg2 + b2 + relu] -> GEMM x BT3 -> sup3 (F=64, cols 40..63 zero)
    fused_ag3<<<TILE_BLOCKS, 256, 0, stream>>>(
        (const uint*)supB, rsp2, edges, b2, BT3, sup3);
    // K5: agg3 + b3 + log_softmax -> out (flattened stream)
    agg_lsm<<<TILE_BLOCKS, 256, 0, stream>>>(sup3, rsp2, edges, b3, out);
}

// Round 10
// 214.629 us; speedup vs baseline: 1.0346x; 1.0346x over previous
//
#include <hip/hip_runtime.h>
#include <math.h>

#define N_NODES 50000
#define N_EDGES 600000
#define NFEAT   256
#define NHID    128
#define NCLASS  40
#define NBUCK 196            // bucket = dst >> 8 (256-node windows)
#define EPB_A 2048           // edges per phase-A block
#define BUCK_CAP 4096        // staging capacity per bucket (mean ~3062)
#define BUCK_WIN 5888        // fixed CSR window per bucket >= BUCK_CAP + 7*256 (mult of 8)
#define BINA_BLOCKS ((N_EDGES + EPB_A - 1) / EPB_A)   // 293
#define CVTW_BLOCKS 224                               // 57344 weight elems / 256
#define GEMM_BLOCKS ((N_NODES + 63) / 64)             // 782   (GEMM1 64-row tiles)
#define TILE_BLOCKS ((N_NODES + 31) / 32)             // 1563  (fused 32-row tiles)

typedef __attribute__((ext_vector_type(8))) short bf16x8;
typedef __attribute__((ext_vector_type(4))) float f32x4;
typedef __attribute__((ext_vector_type(2))) float f32x2;

__device__ inline ushort f2bf(float f) {   // RNE, finite inputs
    uint u = __float_as_uint(f);
    uint r = (u + 0x7fffu + ((u >> 16) & 1u)) >> 16;
    return (ushort)r;
}

// ---------------------------------------------------------------------------
// K1: blocks [0, BINA_BLOCKS) bin edges by 256-node bucket into fixed-capacity
// staging regions (record: uint = (bf16(w)<<16) | src; entry {rec, dst&255}).
// Blocks [BINA_BLOCKS, +CVTW_BLOCKS) convert the three weight matrices to
// transposed bf16.
__global__ __launch_bounds__(256) void binA_cvtw(const int* __restrict__ src,
                                                 const int* __restrict__ dst,
                                                 const float* __restrict__ w,
                                                 int* __restrict__ bucket_cnt,
                                                 int2* __restrict__ staging, int E,
                                                 const float* __restrict__ W1,
                                                 const float* __restrict__ W2,
                                                 const float* __restrict__ W3,
                                                 ushort* __restrict__ BT1,
                                                 ushort* __restrict__ BT2,
                                                 ushort* __restrict__ BT3) {
    int tid = threadIdx.x;
    if ((int)blockIdx.x >= BINA_BLOCKS) {
        int idx = ((int)blockIdx.x - BINA_BLOCKS) * 256 + tid;
        if (idx < 32768) {                       // BT1: 128x256 from W1[256x128]
            int nr = idx >> 8, k = idx & 255;
            BT1[idx] = f2bf(W1[(size_t)k * 128 + nr]);
        } else if (idx < 49152) {                // BT2: 128x128 from W2[128x128]
            int t = idx - 32768;
            int nr = t >> 7, k = t & 127;
            BT2[t] = f2bf(W2[(size_t)k * 128 + nr]);
        } else if (idx < 57344) {                // BT3: 64x128 from W3[128x40], zero-pad
            int t = idx - 49152;
            int nr = t >> 7, k = t & 127;
            BT3[t] = (nr < 40) ? f2bf(W3[(size_t)k * 40 + nr]) : (ushort)0;
        }
        return;
    }
    __shared__ int lh[NBUCK];
    for (int b = tid; b < NBUCK; b += 256) lh[b] = 0;
    __syncthreads();
    int base = blockIdx.x * EPB_A;
    int d[8];
    #pragma unroll
    for (int j = 0; j < 8; ++j) {
        int i = base + j * 256 + tid;
        d[j] = (i < E) ? dst[i] : -1;
        if (d[j] >= 0) atomicAdd(&lh[d[j] >> 8], 1);
    }
    __syncthreads();
    for (int b = tid; b < NBUCK; b += 256) {
        int c = lh[b];
        lh[b] = c ? (b * BUCK_CAP + atomicAdd(&bucket_cnt[b], c)) : 0;
    }
    __syncthreads();
    #pragma unroll
    for (int j = 0; j < 8; ++j) {
        int i = base + j * 256 + tid;
        if (d[j] >= 0) {
            int slot = atomicAdd(&lh[d[j] >> 8], 1);
            uint rec = ((uint)f2bf(w[i]) << 16) | (uint)src[i];
            staging[slot] = make_int2((int)rec, d[j] & 255);
        }
    }
}

// ---------------------------------------------------------------------------
// GEMM1 body, ROUND-10: full 64x256 A-panel staged to LDS ONCE (fused
// fp32->bf16, +8 ushort row pad -> 2-way bank alias only), B-fragments read
// DIRECTLY from the 64KB L2-hot BT1, all 64 MFMAs under a single barrier
// (was: 8 K-steps x 2 barriers + b_s staging).
__device__ __forceinline__ void gemm1_body(const float* __restrict__ x,
                                           const ushort* __restrict__ BT1,
                                           ushort* __restrict__ supA, int row0) {
    __shared__ ushort a_s[64][264];    // 64 rows x 256 k, +8 pad
    int tid = threadIdx.x;
    int wave = tid >> 6, lane = tid & 63;
    {   // stage: thread t -> row t>>2, 64-col quarter (t&3)*64
        int r = tid >> 2, c0 = (tid & 3) * 64;
        int gr = row0 + r; if (gr >= N_NODES) gr = N_NODES - 1;  // clamp, store-guarded
        const float* sp = x + (size_t)gr * 256 + c0;
        #pragma unroll
        for (int j = 0; j < 8; ++j) {
            float4 v0 = *(const float4*)(sp + j * 8);
            float4 v1 = *(const float4*)(sp + j * 8 + 4);
            ushort4 o0, o1;
            o0.x = f2bf(v0.x); o0.y = f2bf(v0.y); o0.z = f2bf(v0.z); o0.w = f2bf(v0.w);
            o1.x = f2bf(v1.x); o1.y = f2bf(v1.y); o1.z = f2bf(v1.z); o1.w = f2bf(v1.w);
            *(ushort4*)(&a_s[r][c0 + j * 8]) = o0;
            *(ushort4*)(&a_s[r][c0 + j * 8 + 4]) = o1;
        }
    }
    __syncthreads();
    int lr = lane & 15, lk = (lane >> 4) * 8;
    f32x4 acc[4][2];
    #pragma unroll
    for (int mt = 0; mt < 4; ++mt)
        #pragma unroll
        for (int nt = 0; nt < 2; ++nt) acc[mt][nt] = (f32x4){0.f, 0.f, 0.f, 0.f};
    #pragma unroll
    for (int ks = 0; ks < 8; ++ks) {
        int k0 = ks * 32;
        bf16x8 bfr[2];
        #pragma unroll
        for (int nt = 0; nt < 2; ++nt)
            bfr[nt] = *(const bf16x8*)(BT1 +
                (size_t)((wave * 2 + nt) * 16 + lr) * 256 + k0 + lk);
        #pragma unroll
        for (int mt = 0; mt < 4; ++mt) {
            bf16x8 afr = *(const bf16x8*)(&a_s[mt * 16 + lr][k0 + lk]);
            #pragma unroll
            for (int nt = 0; nt < 2; ++nt)
                acc[mt][nt] = __builtin_amdgcn_mfma_f32_16x16x32_bf16(
                    afr, bfr[nt], acc[mt][nt], 0, 0, 0);
        }
    }
    // C/D layout: col = lane&15, row = (lane>>4)*4 + i
    int col0 = wave * 32;
    #pragma unroll
    for (int mt = 0; mt < 4; ++mt) {
        int gr0 = row0 + mt * 16 + (lane >> 4) * 4;
        #pragma unroll
        for (int nt = 0; nt < 2; ++nt) {
            int gc = col0 + nt * 16 + lr;
            #pragma unroll
            for (int i = 0; i < 4; ++i) {
                int gr = gr0 + i;
                if (gr < N_NODES)
                    supA[(size_t)gr * 128 + gc] = f2bf(acc[mt][nt][i]);
            }
        }
    }
}

// ---------------------------------------------------------------------------
// K2: blocks [0, NBUCK) do self-contained per-bucket scan+scatter into FIXED
// windows (gaps never read -> no global prefix). Blocks [NBUCK, +782) run
// GEMM1 (x fp32 -> supA bf16), overlapping the CSR tail.
// Scan: shfl_up wave scan + 4-entry cross-wave combine (1 barrier).
__global__ __launch_bounds__(256) void scan_gemm1(const int* __restrict__ bucket_cnt,
                                                  const int2* __restrict__ staging,
                                                  int2* __restrict__ rsp2,
                                                  uint* __restrict__ edges,
                                                  const float* __restrict__ x,
                                                  const ushort* __restrict__ BT1,
                                                  ushort* __restrict__ supA) {
    if ((int)blockIdx.x >= NBUCK) {
        gemm1_body(x, BT1, supA, ((int)blockIdx.x - NBUCK) * 64);
        return;
    }
    __shared__ int hist[256];
    __shared__ int lcur[256];
    __shared__ int wsum[4];
    int tid = threadIdx.x;
    hist[tid] = 0;
    __syncthreads();
    int b = blockIdx.x;
    int c = bucket_cnt[b];
    const int2* st = staging + (size_t)b * BUCK_CAP;
    for (int p = tid; p < c; p += 256) atomicAdd(&hist[st[p].y], 1);
    __syncthreads();
    int v = (hist[tid] + 7) & ~7;   // pad per-node count to multiple of 8
    int lane = tid & 63, wv = tid >> 6;
    int s = v;                      // wave-level inclusive scan (no barriers)
    #pragma unroll
    for (int off = 1; off < 64; off <<= 1) {
        int t = __shfl_up(s, off, 64);
        if (lane >= off) s += t;
    }
    if (lane == 63) wsum[wv] = s;
    __syncthreads();
    int woff = 0;
    #pragma unroll
    for (int j = 0; j < 4; ++j) woff += (j < wv) ? wsum[j] : 0;
    int tot = wsum[0] + wsum[1] + wsum[2] + wsum[3];
    int bb = b * BUCK_WIN;
    int ex = s - v + woff + bb;     // exclusive scan + bucket base
    int i = b * 256 + tid;
    if (i < N_NODES) rsp2[i] = make_int2(ex, ex + v);
    lcur[tid] = ex;
    __syncthreads();
    int e0 = bb + tot;
    for (int p = bb + tid; p < e0; p += 256) edges[p] = 0;   // covers padding
    __syncthreads();
    for (int p = tid; p < c; p += 256) {
        int2 r = st[p];
        int slot = atomicAdd(&lcur[r.y], 1);
        edges[slot] = (uint)r.x;
    }
}

// ---------------------------------------------------------------------------
// Flattened-stream engine, ROUND-8 configuration (proven best): scalarized
// record path (3 rotating SGPR record buffers via readfirstlane'd base),
// depth-2 gather pipeline (2 value buffers), 6-phase rotation.

#define LDREC_S(R, POS) do { \
    int _ub = __builtin_amdgcn_readfirstlane(POS); \
    _Pragma("unroll") \
    for (int _i = 0; _i < 16; ++_i) R[_i] = edges[_ub + _i]; \
} while (0)

#define GATHER_S(P, R) do { \
    _Pragma("unroll") \
    for (int _j = 0; _j < 16; ++_j) { \
        uint _idx = R[_j] & 0xffffu; \
        _idx = (_idx < N_NODES) ? _idx : (N_NODES - 1);  /* SALU clamp */ \
        P[_j] = sup[(size_t)_idx * 64 + lane]; \
    } \
} while (0)

#define FLUSH_A() do { \
    uint _pk = ((uint)f2bf(fmaxf(acc2.y + by, 0.f)) << 16) \
             |  (uint)f2bf(fmaxf(acc2.x + bx, 0.f)); \
    *(uint*)(&a4_s[ks][(wave * 8 + cur) * 40 + kk]) = _pk; \
    acc2 = (f32x2){0.f, 0.f}; \
    ++cur; \
    e_cur = (cur < 8) ? e_s[wave][cur + 1] : 0x7fffffff; \
} while (0)

#define FMA_A(QB, P, R) do { \
    _Pragma("unroll") \
    for (int _g = 0; _g < 2; ++_g) { \
        int _qg = (QB) + _g * 8; \
        while (cur < 8 && _qg >= e_cur) FLUSH_A(); \
        if (_qg < QE) { \
            _Pragma("unroll") \
            for (int _j = 0; _j < 8; ++_j) { \
                uint _pv = P[_g * 8 + _j]; \
                float _w = __uint_as_float(R[_g * 8 + _j] & 0xffff0000u); \
                f32x2 _v; \
                _v.x = __uint_as_float(_pv << 16); \
                _v.y = __uint_as_float(_pv & 0xffff0000u); \
                acc2 += _v * (f32x2){_w, _w}; \
            } \
        } \
    } \
} while (0)

template<int NT>
__device__ __forceinline__ void fused_body(const uint* __restrict__ sup,
                                           const int2* __restrict__ rsp2,
                                           const uint* __restrict__ edges,
                                           const float* __restrict__ bias,
                                           const ushort* __restrict__ BT,
                                           int Nout,
                                           ushort* __restrict__ Cout) {
    __shared__ ushort a4_s[4][32 * 40];
    __shared__ int e_s[4][9];      // [0]=stream start; [i+1]=end of node i
    int tid = threadIdx.x;
    int wave = tid >> 6, lane = tid & 63;
    int row0 = blockIdx.x * 32;
    int nfirst = row0 + wave * 8;
    float bx = bias[2 * lane], by = bias[2 * lane + 1];
    int ks = lane >> 4;            // k-subtile of this lane's feature pair
    int kk = 2 * (lane & 15);      // k offset within the subtile

    if (lane < 8) {
        int nd = nfirst + lane; if (nd >= N_NODES) nd = N_NODES - 1;
        int2 t = rsp2[nd];
        e_s[wave][lane + 1] = t.y;
        if (lane == 0) e_s[wave][0] = t.x;
    }
    __syncthreads();
    int Q = e_s[wave][0], QE = e_s[wave][8];
    int cur = 0, e_cur = e_s[wave][1];
    f32x2 acc2 = (f32x2){0.f, 0.f};

    uint ra[16], rb[16], rc[16];   // uniform records -> SGPR candidates
    uint pa[16], pb[16];
    int q = Q;
    // prologue (over-reads clamped/guarded; stay inside workspace)
    LDREC_S(ra, q);
    GATHER_S(pa, ra);
    LDREC_S(rb, q + 16);
    while (q < QE) {
        // 6-phase rotation: chunk i uses record buf i%3, value buf i%2
        GATHER_S(pb, rb); LDREC_S(rc, q + 32); FMA_A(q, pa, ra);
        q += 16; if (q >= QE) break;
        GATHER_S(pa, rc); LDREC_S(ra, q + 32); FMA_A(q, pb, rb);
        q += 16; if (q >= QE) break;
        GATHER_S(pb, ra); LDREC_S(rb, q + 32); FMA_A(q, pa, rc);
        q += 16; if (q >= QE) break;
        GATHER_S(pa, rb); LDREC_S(rc, q + 32); FMA_A(q, pb, ra);
        q += 16; if (q >= QE) break;
        GATHER_S(pb, rc); LDREC_S(ra, q + 32); FMA_A(q, pa, rb);
        q += 16; if (q >= QE) break;
        GATHER_S(pa, ra); LDREC_S(rb, q + 32); FMA_A(q, pb, rc);
        q += 16;
    }
    while (cur < 8) FLUSH_A();                // finalize remaining nodes
    __syncthreads();

    // GEMM: C[32 x Nout] = A(LDS) @ BT^T, K = 128.
    int lr = lane & 15, lk = (lane >> 4) * 8;
    f32x4 acc[2][NT];
    #pragma unroll
    for (int mt = 0; mt < 2; ++mt)
        #pragma unroll
        for (int nt = 0; nt < NT; ++nt) acc[mt][nt] = (f32x4){0.f, 0.f, 0.f, 0.f};
    #pragma unroll
    for (int ksi = 0; ksi < 4; ++ksi) {
        int k0 = ksi * 32;
        bf16x8 bfr[NT];
        #pragma unroll
        for (int nt = 0; nt < NT; ++nt)
            bfr[nt] = *(const bf16x8*)(BT +
                (size_t)((wave * NT + nt) * 16 + lr) * 128 + k0 + lk);
        #pragma unroll
        for (int mt = 0; mt < 2; ++mt) {
            bf16x8 afr = *(const bf16x8*)(&a4_s[ksi][(mt * 16 + lr) * 40 + lk]);
            #pragma unroll
            for (int nt = 0; nt < NT; ++nt)
                acc[mt][nt] = __builtin_amdgcn_mfma_f32_16x16x32_bf16(
                    afr, bfr[nt], acc[mt][nt], 0, 0, 0);
        }
    }
    int col0 = wave * NT * 16;
    #pragma unroll
    for (int mt = 0; mt < 2; ++mt) {
        int gr0 = row0 + mt * 16 + (lane >> 4) * 4;
        #pragma unroll
        for (int nt = 0; nt < NT; ++nt) {
            int gc = col0 + nt * 16 + lr;
            #pragma unroll
            for (int i = 0; i < 4; ++i) {
                int gr = gr0 + i;
                if (gr < N_NODES && gc < Nout)
                    Cout[(size_t)gr * Nout + gc] = f2bf(acc[mt][nt][i]);
            }
        }
    }
}

__global__ __launch_bounds__(256) void fused_ag2(const uint* __restrict__ sup,
                                                 const int2* __restrict__ rsp2,
                                                 const uint* __restrict__ edges,
                                                 const float* __restrict__ bias,
                                                 const ushort* __restrict__ BT,
                                                 ushort* __restrict__ Cout) {
    fused_body<2>(sup, rsp2, edges, bias, BT, 128, Cout);
}

__global__ __launch_bounds__(256) void fused_ag3(const uint* __restrict__ sup,
                                                 const int2* __restrict__ rsp2,
                                                 const uint* __restrict__ edges,
                                                 const float* __restrict__ bias,
                                                 const ushort* __restrict__ BT,
                                                 ushort* __restrict__ Cout) {
    fused_body<1>(sup, rsp2, edges, bias, BT, 40, Cout);   // F=40 packed rows
}

// ---------------------------------------------------------------------------
// Layer 3 aggregation + bias + log_softmax, flattened-stream, scalarized
// records, depth-2 pipeline. sup3 is F=40 PACKED rows (80 B); lanes >= 40
// gather lane 39 (discarded at flush).

#define GATHER_L(P, R) do { \
    _Pragma("unroll") \
    for (int _j = 0; _j < 16; ++_j) { \
        uint _idx = R[_j] & 0xffffu; \
        _idx = (_idx < N_NODES) ? _idx : (N_NODES - 1); \
        P[_j] = __uint_as_float((uint)sup[(size_t)_idx * 40 + lf] << 16); \
    } \
} while (0)

#define FLUSH_L() do { \
    int _node = nfirst + cur; \
    float _v = (lane < 40) ? acc1 + bl : -INFINITY; \
    float _m = _v; \
    _Pragma("unroll") \
    for (int _o = 32; _o; _o >>= 1) _m = fmaxf(_m, __shfl_xor(_m, _o, 64)); \
    float _ex = (lane < 40) ? expf(_v - _m) : 0.f; \
    float _s = _ex; \
    _Pragma("unroll") \
    for (int _o = 32; _o; _o >>= 1) _s += __shfl_xor(_s, _o, 64); \
    float _ls = logf(_s); \
    if (lane < 40 && _node < N_NODES) \
        out[(size_t)_node * 40 + lane] = _v - _m - _ls; \
    acc1 = 0.f; \
    ++cur; \
    e_cur = (cur < 8) ? e_s[wave][cur + 1] : 0x7fffffff; \
} while (0)

#define FMA_L(QB, P, R) do { \
    _Pragma("unroll") \
    for (int _g = 0; _g < 2; ++_g) { \
        int _qg = (QB) + _g * 8; \
        while (cur < 8 && _qg >= e_cur) FLUSH_L(); \
        if (_qg < QE) { \
            _Pragma("unroll") \
            for (int _j = 0; _j < 8; ++_j) \
                acc1 += P[_g * 8 + _j] * \
                        __uint_as_float(R[_g * 8 + _j] & 0xffff0000u); \
        } \
    } \
} while (0)

__global__ __launch_bounds__(256) void agg_lsm(const ushort* __restrict__ sup,
                                               const int2* __restrict__ rsp2,
                                               const uint* __restrict__ edges,
                                               const float* __restrict__ bias,
                                               float* __restrict__ out) {
    __shared__ int e_s[4][9];
    int tid = threadIdx.x;
    int wave = tid >> 6, lane = tid & 63;
    int nfirst = blockIdx.x * 32 + wave * 8;
    float bl = (lane < 40) ? bias[lane] : 0.f;
    int lf = (lane < 40) ? lane : 39;
    if (lane < 8) {
        int nd = nfirst + lane; if (nd >= N_NODES) nd = N_NODES - 1;
        int2 t = rsp2[nd];
        e_s[wave][lane + 1] = t.y;
        if (lane == 0) e_s[wave][0] = t.x;
    }
    __syncthreads();
    int Q = e_s[wave][0], QE = e_s[wave][8];
    int cur = 0, e_cur = e_s[wave][1];
    float acc1 = 0.f;

    uint ra[16], rb[16], rc[16];
    float pa[16], pb[16];
    int q = Q;
    LDREC_S(ra, q);
    GATHER_L(pa, ra);
    LDREC_S(rb, q + 16);
    while (q < QE) {
        GATHER_L(pb, rb); LDREC_S(rc, q + 32); FMA_L(q, pa, ra);
        q += 16; if (q >= QE) break;
        GATHER_L(pa, rc); LDREC_S(ra, q + 32); FMA_L(q, pb, rb);
        q += 16; if (q >= QE) break;
        GATHER_L(pb, ra); LDREC_S(rb, q + 32); FMA_L(q, pa, rc);
        q += 16; if (q >= QE) break;
        GATHER_L(pa, rb); LDREC_S(rc, q + 32); FMA_L(q, pb, ra);
        q += 16; if (q >= QE) break;
        GATHER_L(pb, rc); LDREC_S(ra, q + 32); FMA_L(q, pa, rb);
        q += 16; if (q >= QE) break;
        GATHER_L(pa, ra); LDREC_S(rb, q + 32); FMA_L(q, pb, rc);
        q += 16;
    }
    while (cur < 8) FLUSH_L();
}

// ---------------------------------------------------------------------------
extern "C" void kernel_launch(void* const* d_in, const int* in_sizes, int n_in,
                              void* d_out, int out_size, void* d_ws, size_t ws_size,
                              hipStream_t stream) {
    const float* x   = (const float*)d_in[0];
    const float* ew  = (const float*)d_in[1];
    const float* W1  = (const float*)d_in[2];
    const float* b1  = (const float*)d_in[3];
    const float* W2  = (const float*)d_in[4];
    const float* b2  = (const float*)d_in[5];
    const float* W3  = (const float*)d_in[6];
    const float* b3  = (const float*)d_in[7];
    const int* esrc  = (const int*)d_in[8];
    const int* edst  = (const int*)d_in[9];
    float* out = (float*)d_out;

    char* ws = (char*)d_ws;
    size_t off = 0;
    auto alloc = [&](size_t bytes) {
        size_t cur = off;
        off += (bytes + 255) & ~(size_t)255;
        return cur;
    };
    int* bucket_cnt = (int*)(ws + alloc(256 * sizeof(int)));
    int2* rsp2   = (int2*)(ws + alloc((size_t)N_NODES * sizeof(int2)));          // 400 KB
    uint* edges  = (uint*)(ws + alloc((size_t)NBUCK * BUCK_WIN * sizeof(uint))); // 4.6 MB
    int2* staging = (int2*)(ws + alloc((size_t)NBUCK * BUCK_CAP * sizeof(int2))); // 6.4 MB
    ushort* BT1  = (ushort*)(ws + alloc(128 * 256 * 2));
    ushort* BT2  = (ushort*)(ws + alloc(128 * 128 * 2));
    ushort* BT3  = (ushort*)(ws + alloc(64 * 128 * 2));
    char* Sreg   = ws + alloc((size_t)N_NODES * 128 * 2);       // 12.8 MB
    char* Hreg   = ws + alloc((size_t)N_NODES * 128 * 2);       // 12.8 MB
    (void)alloc((size_t)66000 * 128 * 2);   // clamp-gather slack past Hreg

    ushort* supA = (ushort*)Sreg;                  // gemm1 out (128/row)
    ushort* supB = (ushort*)Hreg;                  // fused ag2 out (128/row)
    ushort* sup3 = (ushort*)Sreg;                  // fused ag3 out (supA dead), 40/row

    hipMemsetAsync(bucket_cnt, 0, 256 * sizeof(int), stream);
    // K1: edge binning || weight conversion
    binA_cvtw<<<BINA_BLOCKS + CVTW_BLOCKS, 256, 0, stream>>>(
        esrc, edst, ew, bucket_cnt, staging, N_EDGES, W1, W2, W3, BT1, BT2, BT3);
    // K2: per-bucket scan+scatter (fixed windows) || GEMM1 (1-barrier, direct-B)
    scan_gemm1<<<NBUCK + GEMM_BLOCKS, 256, 0, stream>>>(
        bucket_cnt, staging, rsp2, edges, x, BT1, supA);
    // K3: [agg1 + b1 + relu] -> GEMM x BT2 -> supB
    fused_ag2<<<TILE_BLOCKS, 256, 0, stream>>>(
        (const uint*)supA, rsp2, edges, b1, BT2, supB);
    // K4: [agg2 + b2 + relu] -> GEMM x BT3 -> sup3 (F=40 packed)
    fused_ag3<<<TILE_BLOCKS, 256, 0, stream>>>(
        (const uint*)supB, rsp2, edges, b2, BT3, sup3);
    // K5: agg3 + b3 + log_softmax -> out (flattened stream)
    agg_lsm<<<TILE_BLOCKS, 256, 0, stream>>>(sup3, rsp2, edges, b3, out);
}

// Round 11
// 212.349 us; speedup vs baseline: 1.0457x; 1.0107x over previous
//
#include <hip/hip_runtime.h>
#include <math.h>

#define N_NODES 50000
#define N_EDGES 600000
#define NFEAT   256
#define NHID    128
#define NCLASS  40
#define NBUCK 196            // bucket = dst >> 8 (256-node windows)
#define EPB_A 4096           // edges per phase-A block (r11: halve atomic count)
#define BUCK_CAP 4096        // staging capacity per bucket (mean ~3062)
#define BUCK_WIN 5888        // fixed CSR window per bucket >= BUCK_CAP + 7*256 (mult of 8)
#define BINA_BLOCKS ((N_EDGES + EPB_A - 1) / EPB_A)   // 147
#define CVTW_BLOCKS 224                               // 57344 weight elems / 256
#define GEMM_BLOCKS ((N_NODES + 63) / 64)             // 782   (GEMM1 64-row tiles)
#define TILE_BLOCKS ((N_NODES + 31) / 32)             // 1563  (fused 32-row tiles)

typedef __attribute__((ext_vector_type(8))) short bf16x8;
typedef __attribute__((ext_vector_type(4))) float f32x4;
typedef __attribute__((ext_vector_type(2))) float f32x2;

__device__ inline ushort f2bf(float f) {   // RNE, finite inputs
    uint u = __float_as_uint(f);
    uint r = (u + 0x7fffu + ((u >> 16) & 1u)) >> 16;
    return (ushort)r;
}

// ---------------------------------------------------------------------------
// K1: blocks [0, BINA_BLOCKS) bin edges by 256-node bucket into fixed-capacity
// staging regions (record: uint = (bf16(w)<<16) | src; entry {rec, dst&255}).
// Blocks [BINA_BLOCKS, +CVTW_BLOCKS) convert the three weight matrices to
// transposed bf16.
__global__ __launch_bounds__(256) void binA_cvtw(const int* __restrict__ src,
                                                 const int* __restrict__ dst,
                                                 const float* __restrict__ w,
                                                 int* __restrict__ bucket_cnt,
                                                 int2* __restrict__ staging, int E,
                                                 const float* __restrict__ W1,
                                                 const float* __restrict__ W2,
                                                 const float* __restrict__ W3,
                                                 ushort* __restrict__ BT1,
                                                 ushort* __restrict__ BT2,
                                                 ushort* __restrict__ BT3) {
    int tid = threadIdx.x;
    if ((int)blockIdx.x >= BINA_BLOCKS) {
        int idx = ((int)blockIdx.x - BINA_BLOCKS) * 256 + tid;
        if (idx < 32768) {                       // BT1: 128x256 from W1[256x128]
            int nr = idx >> 8, k = idx & 255;
            BT1[idx] = f2bf(W1[(size_t)k * 128 + nr]);
        } else if (idx < 49152) {                // BT2: 128x128 from W2[128x128]
            int t = idx - 32768;
            int nr = t >> 7, k = t & 127;
            BT2[t] = f2bf(W2[(size_t)k * 128 + nr]);
        } else if (idx < 57344) {                // BT3: 64x128 from W3[128x40], zero-pad
            int t = idx - 49152;
            int nr = t >> 7, k = t & 127;
            BT3[t] = (nr < 40) ? f2bf(W3[(size_t)k * 40 + nr]) : (ushort)0;
        }
        return;
    }
    __shared__ int lh[NBUCK];
    for (int b = tid; b < NBUCK; b += 256) lh[b] = 0;
    __syncthreads();
    int base = blockIdx.x * EPB_A;
    int d[16];
    #pragma unroll
    for (int j = 0; j < 16; ++j) {
        int i = base + j * 256 + tid;
        d[j] = (i < E) ? dst[i] : -1;
        if (d[j] >= 0) atomicAdd(&lh[d[j] >> 8], 1);
    }
    __syncthreads();
    for (int b = tid; b < NBUCK; b += 256) {
        int c = lh[b];
        lh[b] = c ? (b * BUCK_CAP + atomicAdd(&bucket_cnt[b], c)) : 0;
    }
    __syncthreads();
    #pragma unroll
    for (int j = 0; j < 16; ++j) {
        int i = base + j * 256 + tid;
        if (d[j] >= 0) {
            int slot = atomicAdd(&lh[d[j] >> 8], 1);
            uint rec = ((uint)f2bf(w[i]) << 16) | (uint)src[i];
            staging[slot] = make_int2((int)rec, d[j] & 255);
        }
    }
}

// ---------------------------------------------------------------------------
// GEMM1 body, ROUND-11: A staged in two 64x128 halves (17.4 KB LDS -> 9
// blocks/CU, vs round-10's 33.8 KB -> 4), B-fragments direct from the 64 KB
// L2-hot BT1, 4 barriers total (was 16 in the generic body).
__device__ __forceinline__ void gemm1_body(const float* __restrict__ x,
                                           const ushort* __restrict__ BT1,
                                           ushort* __restrict__ supA, int row0) {
    __shared__ ushort a_s[64][136];    // 64 rows x 128 k-half, +8 pad
    int tid = threadIdx.x;
    int wave = tid >> 6, lane = tid & 63;
    int lr = lane & 15, lk = (lane >> 4) * 8;
    f32x4 acc[4][2];
    #pragma unroll
    for (int mt = 0; mt < 4; ++mt)
        #pragma unroll
        for (int nt = 0; nt < 2; ++nt) acc[mt][nt] = (f32x4){0.f, 0.f, 0.f, 0.f};
    int r = tid >> 2, c0 = (tid & 3) * 32;
    int gr = row0 + r; if (gr >= N_NODES) gr = N_NODES - 1;  // clamp, store-guarded
    #pragma unroll
    for (int h = 0; h < 2; ++h) {
        const float* sp = x + (size_t)gr * 256 + h * 128 + c0;
        #pragma unroll
        for (int j = 0; j < 4; ++j) {
            float4 v0 = *(const float4*)(sp + j * 8);
            float4 v1 = *(const float4*)(sp + j * 8 + 4);
            ushort4 o0, o1;
            o0.x = f2bf(v0.x); o0.y = f2bf(v0.y); o0.z = f2bf(v0.z); o0.w = f2bf(v0.w);
            o1.x = f2bf(v1.x); o1.y = f2bf(v1.y); o1.z = f2bf(v1.z); o1.w = f2bf(v1.w);
            *(ushort4*)(&a_s[r][c0 + j * 8]) = o0;
            *(ushort4*)(&a_s[r][c0 + j * 8 + 4]) = o1;
        }
        __syncthreads();
        #pragma unroll
        for (int ks = 0; ks < 4; ++ks) {
            int k0 = ks * 32;
            bf16x8 bfr[2];
            #pragma unroll
            for (int nt = 0; nt < 2; ++nt)
                bfr[nt] = *(const bf16x8*)(BT1 +
                    (size_t)((wave * 2 + nt) * 16 + lr) * 256 + h * 128 + k0 + lk);
            #pragma unroll
            for (int mt = 0; mt < 4; ++mt) {
                bf16x8 afr = *(const bf16x8*)(&a_s[mt * 16 + lr][k0 + lk]);
                #pragma unroll
                for (int nt = 0; nt < 2; ++nt)
                    acc[mt][nt] = __builtin_amdgcn_mfma_f32_16x16x32_bf16(
                        afr, bfr[nt], acc[mt][nt], 0, 0, 0);
            }
        }
        __syncthreads();
    }
    // C/D layout: col = lane&15, row = (lane>>4)*4 + i
    int col0 = wave * 32;
    #pragma unroll
    for (int mt = 0; mt < 4; ++mt) {
        int gr0 = row0 + mt * 16 + (lane >> 4) * 4;
        #pragma unroll
        for (int nt = 0; nt < 2; ++nt) {
            int gc = col0 + nt * 16 + lr;
            #pragma unroll
            for (int i = 0; i < 4; ++i) {
                int grr = gr0 + i;
                if (grr < N_NODES)
                    supA[(size_t)grr * 128 + gc] = f2bf(acc[mt][nt][i]);
            }
        }
    }
}

// ---------------------------------------------------------------------------
// K2: blocks [0, NBUCK) do self-contained per-bucket scan+scatter into FIXED
// windows (gaps never read -> no global prefix). Blocks [NBUCK, +782) run
// GEMM1 (x fp32 -> supA bf16), overlapping the CSR tail.
// Scan: shfl_up wave scan + 4-entry cross-wave combine (1 barrier).
__global__ __launch_bounds__(256) void scan_gemm1(const int* __restrict__ bucket_cnt,
                                                  const int2* __restrict__ staging,
                                                  int2* __restrict__ rsp2,
                                                  uint* __restrict__ edges,
                                                  const float* __restrict__ x,
                                                  const ushort* __restrict__ BT1,
                                                  ushort* __restrict__ supA) {
    if ((int)blockIdx.x >= NBUCK) {
        gemm1_body(x, BT1, supA, ((int)blockIdx.x - NBUCK) * 64);
        return;
    }
    __shared__ int hist[256];
    __shared__ int lcur[256];
    __shared__ int wsum[4];
    int tid = threadIdx.x;
    hist[tid] = 0;
    __syncthreads();
    int b = blockIdx.x;
    int c = bucket_cnt[b];
    const int2* st = staging + (size_t)b * BUCK_CAP;
    for (int p = tid; p < c; p += 256) atomicAdd(&hist[st[p].y], 1);
    __syncthreads();
    int v = (hist[tid] + 7) & ~7;   // pad per-node count to multiple of 8
    int lane = tid & 63, wv = tid >> 6;
    int s = v;                      // wave-level inclusive scan (no barriers)
    #pragma unroll
    for (int off = 1; off < 64; off <<= 1) {
        int t = __shfl_up(s, off, 64);
        if (lane >= off) s += t;
    }
    if (lane == 63) wsum[wv] = s;
    __syncthreads();
    int woff = 0;
    #pragma unroll
    for (int j = 0; j < 4; ++j) woff += (j < wv) ? wsum[j] : 0;
    int tot = wsum[0] + wsum[1] + wsum[2] + wsum[3];
    int bb = b * BUCK_WIN;
    int ex = s - v + woff + bb;     // exclusive scan + bucket base
    int i = b * 256 + tid;
    if (i < N_NODES) rsp2[i] = make_int2(ex, ex + v);
    lcur[tid] = ex;
    __syncthreads();
    int e0 = bb + tot;
    for (int p = bb + tid; p < e0; p += 256) edges[p] = 0;   // covers padding
    __syncthreads();
    for (int p = tid; p < c; p += 256) {
        int2 r = st[p];
        int slot = atomicAdd(&lcur[r.y], 1);
        edges[slot] = (uint)r.x;
    }
}

// ---------------------------------------------------------------------------
// Flattened-stream engine, ROUND-8 configuration (proven best): scalarized
// record path (3 rotating SGPR record buffers via readfirstlane'd base),
// depth-2 gather pipeline (2 value buffers), 6-phase rotation.

#define LDREC_S(R, POS) do { \
    int _ub = __builtin_amdgcn_readfirstlane(POS); \
    _Pragma("unroll") \
    for (int _i = 0; _i < 16; ++_i) R[_i] = edges[_ub + _i]; \
} while (0)

#define GATHER_S(P, R) do { \
    _Pragma("unroll") \
    for (int _j = 0; _j < 16; ++_j) { \
        uint _idx = R[_j] & 0xffffu; \
        _idx = (_idx < N_NODES) ? _idx : (N_NODES - 1);  /* SALU clamp */ \
        P[_j] = sup[(size_t)_idx * 64 + lane]; \
    } \
} while (0)

#define FLUSH_A() do { \
    uint _pk = ((uint)f2bf(fmaxf(acc2.y + by, 0.f)) << 16) \
             |  (uint)f2bf(fmaxf(acc2.x + bx, 0.f)); \
    *(uint*)(&a4_s[ks][(wave * 8 + cur) * 40 + kk]) = _pk; \
    acc2 = (f32x2){0.f, 0.f}; \
    ++cur; \
    e_cur = (cur < 8) ? e_s[wave][cur + 1] : 0x7fffffff; \
} while (0)

#define FMA_A(QB, P, R) do { \
    _Pragma("unroll") \
    for (int _g = 0; _g < 2; ++_g) { \
        int _qg = (QB) + _g * 8; \
        while (cur < 8 && _qg >= e_cur) FLUSH_A(); \
        if (_qg < QE) { \
            _Pragma("unroll") \
            for (int _j = 0; _j < 8; ++_j) { \
                uint _pv = P[_g * 8 + _j]; \
                float _w = __uint_as_float(R[_g * 8 + _j] & 0xffff0000u); \
                f32x2 _v; \
                _v.x = __uint_as_float(_pv << 16); \
                _v.y = __uint_as_float(_pv & 0xffff0000u); \
                acc2 += _v * (f32x2){_w, _w}; \
            } \
        } \
    } \
} while (0)

template<int NT>
__device__ __forceinline__ void fused_body(const uint* __restrict__ sup,
                                           const int2* __restrict__ rsp2,
                                           const uint* __restrict__ edges,
                                           const float* __restrict__ bias,
                                           const ushort* __restrict__ BT,
                                           int Nout,
                                           ushort* __restrict__ Cout) {
    __shared__ ushort a4_s[4][32 * 40];
    __shared__ int e_s[4][9];      // [0]=stream start; [i+1]=end of node i
    int tid = threadIdx.x;
    int wave = tid >> 6, lane = tid & 63;
    int row0 = blockIdx.x * 32;
    int nfirst = row0 + wave * 8;
    float bx = bias[2 * lane], by = bias[2 * lane + 1];
    int ks = lane >> 4;            // k-subtile of this lane's feature pair
    int kk = 2 * (lane & 15);      // k offset within the subtile

    if (lane < 8) {
        int nd = nfirst + lane; if (nd >= N_NODES) nd = N_NODES - 1;
        int2 t = rsp2[nd];
        e_s[wave][lane + 1] = t.y;
        if (lane == 0) e_s[wave][0] = t.x;
    }
    __syncthreads();
    int Q = e_s[wave][0], QE = e_s[wave][8];
    int cur = 0, e_cur = e_s[wave][1];
    f32x2 acc2 = (f32x2){0.f, 0.f};

    uint ra[16], rb[16], rc[16];   // uniform records -> SGPR candidates
    uint pa[16], pb[16];
    int q = Q;
    // prologue (over-reads clamped/guarded; stay inside workspace)
    LDREC_S(ra, q);
    GATHER_S(pa, ra);
    LDREC_S(rb, q + 16);
    while (q < QE) {
        // 6-phase rotation: chunk i uses record buf i%3, value buf i%2
        GATHER_S(pb, rb); LDREC_S(rc, q + 32); FMA_A(q, pa, ra);
        q += 16; if (q >= QE) break;
        GATHER_S(pa, rc); LDREC_S(ra, q + 32); FMA_A(q, pb, rb);
        q += 16; if (q >= QE) break;
        GATHER_S(pb, ra); LDREC_S(rb, q + 32); FMA_A(q, pa, rc);
        q += 16; if (q >= QE) break;
        GATHER_S(pa, rb); LDREC_S(rc, q + 32); FMA_A(q, pb, ra);
        q += 16; if (q >= QE) break;
        GATHER_S(pb, rc); LDREC_S(ra, q + 32); FMA_A(q, pa, rb);
        q += 16; if (q >= QE) break;
        GATHER_S(pa, ra); LDREC_S(rb, q + 32); FMA_A(q, pb, rc);
        q += 16;
    }
    while (cur < 8) FLUSH_A();                // finalize remaining nodes
    __syncthreads();

    // GEMM: C[32 x Nout] = A(LDS) @ BT^T, K = 128.
    int lr = lane & 15, lk = (lane >> 4) * 8;
    f32x4 acc[2][NT];
    #pragma unroll
    for (int mt = 0; mt < 2; ++mt)
        #pragma unroll
        for (int nt = 0; nt < NT; ++nt) acc[mt][nt] = (f32x4){0.f, 0.f, 0.f, 0.f};
    #pragma unroll
    for (int ksi = 0; ksi < 4; ++ksi) {
        int k0 = ksi * 32;
        bf16x8 bfr[NT];
        #pragma unroll
        for (int nt = 0; nt < NT; ++nt)
            bfr[nt] = *(const bf16x8*)(BT +
                (size_t)((wave * NT + nt) * 16 + lr) * 128 + k0 + lk);
        #pragma unroll
        for (int mt = 0; mt < 2; ++mt) {
            bf16x8 afr = *(const bf16x8*)(&a4_s[ksi][(mt * 16 + lr) * 40 + lk]);
            #pragma unroll
            for (int nt = 0; nt < NT; ++nt)
                acc[mt][nt] = __builtin_amdgcn_mfma_f32_16x16x32_bf16(
                    afr, bfr[nt], acc[mt][nt], 0, 0, 0);
        }
    }
    int col0 = wave * NT * 16;
    #pragma unroll
    for (int mt = 0; mt < 2; ++mt) {
        int gr0 = row0 + mt * 16 + (lane >> 4) * 4;
        #pragma unroll
        for (int nt = 0; nt < NT; ++nt) {
            int gc = col0 + nt * 16 + lr;
            #pragma unroll
            for (int i = 0; i < 4; ++i) {
                int gr = gr0 + i;
                if (gr < N_NODES && gc < Nout)
                    Cout[(size_t)gr * Nout + gc] = f2bf(acc[mt][nt][i]);
            }
        }
    }
}

__global__ __launch_bounds__(256) void fused_ag2(const uint* __restrict__ sup,
                                                 const int2* __restrict__ rsp2,
                                                 const uint* __restrict__ edges,
                                                 const float* __restrict__ bias,
                                                 const ushort* __restrict__ BT,
                                                 ushort* __restrict__ Cout) {
    fused_body<2>(sup, rsp2, edges, bias, BT, 128, Cout);
}

__global__ __launch_bounds__(256) void fused_ag3(const uint* __restrict__ sup,
                                                 const int2* __restrict__ rsp2,
                                                 const uint* __restrict__ edges,
                                                 const float* __restrict__ bias,
                                                 const ushort* __restrict__ BT,
                                                 ushort* __restrict__ Cout) {
    fused_body<1>(sup, rsp2, edges, bias, BT, 40, Cout);   // F=40 packed rows
}

// ---------------------------------------------------------------------------
// Layer 3 aggregation + bias + log_softmax, flattened-stream, scalarized
// records, depth-2 pipeline. sup3 is F=40 PACKED rows (80 B); lanes >= 40
// gather lane 39 (discarded at flush).

#define GATHER_L(P, R) do { \
    _Pragma("unroll") \
    for (int _j = 0; _j < 16; ++_j) { \
        uint _idx = R[_j] & 0xffffu; \
        _idx = (_idx < N_NODES) ? _idx : (N_NODES - 1); \
        P[_j] = __uint_as_float((uint)sup[(size_t)_idx * 40 + lf] << 16); \
    } \
} while (0)

#define FLUSH_L() do { \
    int _node = nfirst + cur; \
    float _v = (lane < 40) ? acc1 + bl : -INFINITY; \
    float _m = _v; \
    _Pragma("unroll") \
    for (int _o = 32; _o; _o >>= 1) _m = fmaxf(_m, __shfl_xor(_m, _o, 64)); \
    float _ex = (lane < 40) ? expf(_v - _m) : 0.f; \
    float _s = _ex; \
    _Pragma("unroll") \
    for (int _o = 32; _o; _o >>= 1) _s += __shfl_xor(_s, _o, 64); \
    float _ls = logf(_s); \
    if (lane < 40 && _node < N_NODES) \
        out[(size_t)_node * 40 + lane] = _v - _m - _ls; \
    acc1 = 0.f; \
    ++cur; \
    e_cur = (cur < 8) ? e_s[wave][cur + 1] : 0x7fffffff; \
} while (0)

#define FMA_L(QB, P, R) do { \
    _Pragma("unroll") \
    for (int _g = 0; _g < 2; ++_g) { \
        int _qg = (QB) + _g * 8; \
        while (cur < 8 && _qg >= e_cur) FLUSH_L(); \
        if (_qg < QE) { \
            _Pragma("unroll") \
            for (int _j = 0; _j < 8; ++_j) \
                acc1 += P[_g * 8 + _j] * \
                        __uint_as_float(R[_g * 8 + _j] & 0xffff0000u); \
        } \
    } \
} while (0)

__global__ __launch_bounds__(256) void agg_lsm(const ushort* __restrict__ sup,
                                               const int2* __restrict__ rsp2,
                                               const uint* __restrict__ edges,
                                               const float* __restrict__ bias,
                                               float* __restrict__ out) {
    __shared__ int e_s[4][9];
    int tid = threadIdx.x;
    int wave = tid >> 6, lane = tid & 63;
    int nfirst = blockIdx.x * 32 + wave * 8;
    float bl = (lane < 40) ? bias[lane] : 0.f;
    int lf = (lane < 40) ? lane : 39;
    if (lane < 8) {
        int nd = nfirst + lane; if (nd >= N_NODES) nd = N_NODES - 1;
        int2 t = rsp2[nd];
        e_s[wave][lane + 1] = t.y;
        if (lane == 0) e_s[wave][0] = t.x;
    }
    __syncthreads();
    int Q = e_s[wave][0], QE = e_s[wave][8];
    int cur = 0, e_cur = e_s[wave][1];
    float acc1 = 0.f;

    uint ra[16], rb[16], rc[16];
    float pa[16], pb[16];
    int q = Q;
    LDREC_S(ra, q);
    GATHER_L(pa, ra);
    LDREC_S(rb, q + 16);
    while (q < QE) {
        GATHER_L(pb, rb); LDREC_S(rc, q + 32); FMA_L(q, pa, ra);
        q += 16; if (q >= QE) break;
        GATHER_L(pa, rc); LDREC_S(ra, q + 32); FMA_L(q, pb, rb);
        q += 16; if (q >= QE) break;
        GATHER_L(pb, ra); LDREC_S(rb, q + 32); FMA_L(q, pa, rc);
        q += 16; if (q >= QE) break;
        GATHER_L(pa, rb); LDREC_S(rc, q + 32); FMA_L(q, pb, ra);
        q += 16; if (q >= QE) break;
        GATHER_L(pb, rc); LDREC_S(ra, q + 32); FMA_L(q, pa, rb);
        q += 16; if (q >= QE) break;
        GATHER_L(pa, ra); LDREC_S(rb, q + 32); FMA_L(q, pb, rc);
        q += 16;
    }
    while (cur < 8) FLUSH_L();
}

// ---------------------------------------------------------------------------
extern "C" void kernel_launch(void* const* d_in, const int* in_sizes, int n_in,
                              void* d_out, int out_size, void* d_ws, size_t ws_size,
                              hipStream_t stream) {
    const float* x   = (const float*)d_in[0];
    const float* ew  = (const float*)d_in[1];
    const float* W1  = (const float*)d_in[2];
    const float* b1  = (const float*)d_in[3];
    const float* W2  = (const float*)d_in[4];
    const float* b2  = (const float*)d_in[5];
    const float* W3  = (const float*)d_in[6];
    const float* b3  = (const float*)d_in[7];
    const int* esrc  = (const int*)d_in[8];
    const int* edst  = (const int*)d_in[9];
    float* out = (float*)d_out;

    char* ws = (char*)d_ws;
    size_t off = 0;
    auto alloc = [&](size_t bytes) {
        size_t cur = off;
        off += (bytes + 255) & ~(size_t)255;
        return cur;
    };
    int* bucket_cnt = (int*)(ws + alloc(256 * sizeof(int)));
    int2* rsp2   = (int2*)(ws + alloc((size_t)N_NODES * sizeof(int2)));          // 400 KB
    uint* edges  = (uint*)(ws + alloc((size_t)NBUCK * BUCK_WIN * sizeof(uint))); // 4.6 MB
    int2* staging = (int2*)(ws + alloc((size_t)NBUCK * BUCK_CAP * sizeof(int2))); // 6.4 MB
    ushort* BT1  = (ushort*)(ws + alloc(128 * 256 * 2));
    ushort* BT2  = (ushort*)(ws + alloc(128 * 128 * 2));
    ushort* BT3  = (ushort*)(ws + alloc(64 * 128 * 2));
    char* Sreg   = ws + alloc((size_t)N_NODES * 128 * 2);       // 12.8 MB
    char* Hreg   = ws + alloc((size_t)N_NODES * 128 * 2);       // 12.8 MB
    (void)alloc((size_t)66000 * 128 * 2);   // clamp-gather slack past Hreg

    ushort* supA = (ushort*)Sreg;                  // gemm1 out (128/row)
    ushort* supB = (ushort*)Hreg;                  // fused ag2 out (128/row)
    ushort* sup3 = (ushort*)Sreg;                  // fused ag3 out (supA dead), 40/row

    hipMemsetAsync(bucket_cnt, 0, 256 * sizeof(int), stream);
    // K1: edge binning || weight conversion
    binA_cvtw<<<BINA_BLOCKS + CVTW_BLOCKS, 256, 0, stream>>>(
        esrc, edst, ew, bucket_cnt, staging, N_EDGES, W1, W2, W3, BT1, BT2, BT3);
    // K2: per-bucket scan+scatter (fixed windows) || GEMM1 (4-barrier, direct-B)
    scan_gemm1<<<NBUCK + GEMM_BLOCKS, 256, 0, stream>>>(
        bucket_cnt, staging, rsp2, edges, x, BT1, supA);
    // K3: [agg1 + b1 + relu] -> GEMM x BT2 -> supB
    fused_ag2<<<TILE_BLOCKS, 256, 0, stream>>>(
        (const uint*)supA, rsp2, edges, b1, BT2, supB);
    // K4: [agg2 + b2 + relu] -> GEMM x BT3 -> sup3 (F=40 packed)
    fused_ag3<<<TILE_BLOCKS, 256, 0, stream>>>(
        (const uint*)supB, rsp2, edges, b2, BT3, sup3);
    // K5: agg3 + b3 + log_softmax -> out (flattened stream)
    agg_lsm<<<TILE_BLOCKS, 256, 0, stream>>>(sup3, rsp2, edges, b3, out);
}